// Round 6
// baseline (126.594 us; speedup 1.0000x reference)
//
#include <hip/hip_runtime.h>
#include <math.h>

#define NPIX 1089
#define DIM 512
#define NIMG 16
#define NLBL 8      // labels 0..6 used, 7 = padding bucket
#define NMASK 6
#define INVT 14.2857142857142857f  // 1/0.07

#define NGRP 72     // 16-row groups per image (72*16 = 1152 padded rows)
#define NROWPAD 1152
#define NT9 9       // 128-row tiles per dim

// Embeddings are unit-normalized by the module, so rn2 == 1 (+-2e-7):
// max-subtract constant, q_l (= cnt_l), totq (= NPIX) collapse.
//
// bfemb fragment-ordered layout (uint4 units):
//   index = ((img*NGRP + g)*16 + kc)*64 + (q*16 + m),  row = g*16+m, hw = kc*32 + q*8
// => any MFMA A/B fragment load is ONE contiguous 1KB wave load, and the
//    same chunk is ONE global_load_lds_dwordx4 wave load into linear LDS.
//
// E9[img][s][1152]: 9 owner-slots per image; each (rowgroup,slot) written by
// exactly ONE epass block (plain stores, no memset, no atomics).
//
// Lessons: R9 -- don't fuse cold tails into hot kernels (LDS/VGPR tax).
// R10/R11 -- standalone trivial kernels cost ~8us+gap; duplicate their work.
// R12 -- epass was L2-latency-bound at 11 waves/CU; widened to 8 waves/block.
// R13 -- LDS-stage per-kc chunks once (global_load_lds w=16, linear) -> -10.7us.
// R16 -- fused ticket tail REGRESSED +17us: device-scope __threadfence per
// block = buffer_wbl2/inv x720 (XCD L2s non-coherent). Keep 3 kernels.
// R17/R18 -- counted-vmcnt pipeline NEUTRAL vs plain syncthreads dbuf
// (reproduces m131-m140); the binding pipe isn't load latency.
// R19 -- LDS-BW audit: staged A+B = 64 KB LDS traffic/kc/block (500 cyc) vs
// MFMA 310 cyc => LDS-bound. Hybrid: A staged (4-way wave reuse), B direct
// global->VGPR prefetch (2-way reuse, L1-hit); LDS 40 KB/kc ~= MFMA; LDS
// 19 KB total -> 4 blocks/CU.
// Budget model: totals == ~88us harness fill poison + ours (~35us):
// packsum ~11 (HBM-floor ~9.5), epass ~9 (floor ~6), imgfinal ~4, gaps ~3.

typedef short v8s __attribute__((ext_vector_type(8)));
typedef float v4f __attribute__((ext_vector_type(4)));

__device__ __forceinline__ float wave_reduce(float x) {
#pragma unroll
  for (int o = 32; o > 0; o >>= 1) x += __shfl_xor(x, o, 64);
  return x;
}
__device__ __forceinline__ unsigned bfbits(float x) {  // fp32 -> bf16 bits, RNE
  unsigned u = __float_as_uint(x);
  return (u + 0x7FFFu + ((u >> 16) & 1u)) >> 16;
}
__device__ __forceinline__ unsigned pk(float lo, float hi) {
  return bfbits(lo) | (bfbits(hi) << 16);
}

// -------- K1: fused labels + pack (fp32 -> fragment-ordered bf16) + partial sums ----
__global__ __launch_bounds__(512) void k_packsum(const float* __restrict__ emb,
                                                 const float* __restrict__ masks,
                                                 uint2* __restrict__ bfemb2,
                                                 float* __restrict__ sums9,
                                                 int* __restrict__ labels,
                                                 float* __restrict__ cnt9,
                                                 unsigned* __restrict__ counter) {
  int b = blockIdx.y;
  int g9 = blockIdx.x >> 1, dh = blockIdx.x & 1;  // 128-row group, 256-dim half
  int tid = threadIdx.x, dd = tid & 63, w4 = tid >> 6, lane = tid & 63;
  __shared__ float msum[NMASK];
  __shared__ int slab[128];
  __shared__ int scnt[NLBL];
  __shared__ float4 red[8 * 8 * 64];  // [l][w4][dd], 64 KB
  if (tid < NMASK) msum[tid] = 0.f;
  if (tid < NLBL) scnt[tid] = 0;
  if (b == 0 && blockIdx.x == 0 && tid == 0) *counter = 0u;
  __syncthreads();
  // per-channel mask sums (active test) -- L2-hot
  {
    float am[NMASK] = {0.f, 0.f, 0.f, 0.f, 0.f, 0.f};
    for (int p = tid; p < NPIX; p += 512) {
#pragma unroll
      for (int c = 0; c < NMASK; c++) am[c] += masks[((size_t)b * NMASK + c) * NPIX + p];
    }
#pragma unroll
    for (int c = 0; c < NMASK; c++) {
      float v = wave_reduce(am[c]);
      if (lane == 0) atomicAdd(&msum[c], v);
    }
  }
  __syncthreads();
  if (tid < 128) {
    int r = g9 * 128 + tid;
    int lab = 7;
    if (r < NPIX) {
      lab = 0;
#pragma unroll
      for (int c = 0; c < NMASK; c++) {
        float mv = masks[((size_t)b * NMASK + c) * NPIX + r];
        if (mv > 0.5f && msum[c] > 0.f) lab = c + 1;  // ascending overwrite == max over hits
      }
    }
    slab[tid] = lab;
    if (dh == 0) {
      labels[b * NROWPAD + r] = lab;
      if (r < NPIX) atomicAdd(&scnt[lab], 1);   // exclude pad rows
    }
  }
  __syncthreads();
  if (dh == 0 && tid < NLBL) cnt9[((size_t)b * NT9 + g9) * NLBL + tid] = (float)scnt[tid];
  float4 fa0 = {0,0,0,0}, fa1 = {0,0,0,0}, fa2 = {0,0,0,0}, fa3 = {0,0,0,0};
  float4 fa4 = {0,0,0,0}, fa5 = {0,0,0,0}, fa6 = {0,0,0,0}, fa7 = {0,0,0,0};
  int kc = dh * 8 + (dd >> 3), q = (dd >> 1) & 3, half = dd & 1;
#pragma unroll
  for (int k = 0; k < 16; k++) {
    int r = g9 * 128 + w4 + k * 8;           // wave-uniform row
    bool v = r < NPIX;
    int rc = v ? r : (NPIX - 1);
    float4 x = ((const float4*)(emb + (size_t)(b * NPIX + rc) * DIM))[dh * 64 + dd];
    if (!v) x = make_float4(0.f, 0.f, 0.f, 0.f);
    uint2 o = make_uint2(pk(x.x, x.y), pk(x.z, x.w));
    bfemb2[((((size_t)(b * NGRP + (r >> 4)) * 16 + kc) * 64) + q * 16 + (r & 15)) * 2 + half] = o;
    int lab = __builtin_amdgcn_readfirstlane(slab[r - g9 * 128]);
    switch (lab) {
      case 0: fa0.x += x.x; fa0.y += x.y; fa0.z += x.z; fa0.w += x.w; break;
      case 1: fa1.x += x.x; fa1.y += x.y; fa1.z += x.z; fa1.w += x.w; break;
      case 2: fa2.x += x.x; fa2.y += x.y; fa2.z += x.z; fa2.w += x.w; break;
      case 3: fa3.x += x.x; fa3.y += x.y; fa3.z += x.z; fa3.w += x.w; break;
      case 4: fa4.x += x.x; fa4.y += x.y; fa4.z += x.z; fa4.w += x.w; break;
      case 5: fa5.x += x.x; fa5.y += x.y; fa5.z += x.z; fa5.w += x.w; break;
      case 6: fa6.x += x.x; fa6.y += x.y; fa6.z += x.z; fa6.w += x.w; break;
      default: fa7.x += x.x; fa7.y += x.y; fa7.z += x.z; fa7.w += x.w; break;
    }
  }
  red[(0 * 8 + w4) * 64 + dd] = fa0; red[(1 * 8 + w4) * 64 + dd] = fa1;
  red[(2 * 8 + w4) * 64 + dd] = fa2; red[(3 * 8 + w4) * 64 + dd] = fa3;
  red[(4 * 8 + w4) * 64 + dd] = fa4; red[(5 * 8 + w4) * 64 + dd] = fa5;
  red[(6 * 8 + w4) * 64 + dd] = fa6; red[(7 * 8 + w4) * 64 + dd] = fa7;
  __syncthreads();
  int l = tid >> 6, d2 = tid & 63;
  float4 s = {0,0,0,0};
#pragma unroll
  for (int ww = 0; ww < 8; ww++) {
    float4 t = red[(l * 8 + ww) * 64 + d2];
    s.x += t.x; s.y += t.y; s.z += t.z; s.w += t.w;
  }
  *(float4*)&sums9[(((size_t)(b * NT9 + g9) * NLBL + l) * DIM) + dh * 256 + d2 * 4] = s;
}

// -------- K2: E-pass, hybrid operand sourcing --------
// 8 waves/block (64x32 per wave). A staged in LDS (4-way wave reuse,
// global_load_lds w=16, 2x8KB double buffer); B read DIRECT global->VGPR
// with 1-step prefetch (2-way reuse -> L1 hit; no LDS cost). Cuts LDS
// traffic 64->40 KB/kc (was the binding pipe, R19). 19 KB LDS -> 4 blk/CU.
__global__ __launch_bounds__(512) void k_epass9(const uint4* __restrict__ bfemb4,
                                                float* __restrict__ E9) {
  int n = blockIdx.x;                          // 45*16 = 720
  int img = ((n & 7) << 1) | ((n >> 3) & 1);   // 2 images per XCD
  int t = n >> 4;                              // 0..44 upper-tri tile
  int it = 0, rem = t;
  while (rem >= NT9 - it) { rem -= NT9 - it; it++; }
  int jt = it + rem;
  int i0 = it * 128, j0 = jt * 128;
  bool diag = (it == jt);
  int tid = threadIdx.x, lane = tid & 63, w = tid >> 6;
  int wm = w >> 2, wn = w & 3;                 // 2 row-waves x 4 col-waves
  int quad = lane >> 4, l15 = lane & 15;
  __shared__ uint4 st[2][8][64];               // 16 KB A staging (double buffer)
  __shared__ float Ered[4][128];               // 4 col-wave partials per row
  __shared__ float Ecol[2][128];               // 2 row-wave partials per col

  // wave w stages A-chunk it*8+w; reads B-chunks jt*8+wn*2+{0,1} direct.
  size_t gA = ((size_t)(img * NGRP + it * 8 + w) * 16) * 64 + lane;
  const uint4* gB0 = bfemb4 + ((size_t)(img * NGRP + jt * 8 + wn * 2 + 0) * 16) * 64 + lane;
  const uint4* gB1 = bfemb4 + ((size_t)(img * NGRP + jt * 8 + wn * 2 + 1) * 16) * 64 + lane;

#define STAGE_A(kc, buf)                                                        \
  __builtin_amdgcn_global_load_lds(                                             \
      (const __attribute__((address_space(1))) void*)(bfemb4 + gA + (kc) * 64), \
      (__attribute__((address_space(3))) void*)&st[buf][w][0], 16, 0, 0);

  v4f acc[4][2];
#pragma unroll
  for (int mf = 0; mf < 4; mf++)
#pragma unroll
    for (int nf = 0; nf < 2; nf++) acc[mf][nf] = (v4f){0.f, 0.f, 0.f, 0.f};

  v8s bc0, bc1, bn0, bn1;
  STAGE_A(0, 0);
  bc0 = *(const v8s*)(gB0);
  bc1 = *(const v8s*)(gB1);
  __syncthreads();  // buf0 staged (drain also retires bc loads)
#pragma unroll
  for (int kc = 0; kc < 16; kc++) {
    int cur = kc & 1;
    if (kc < 15) {
      STAGE_A(kc + 1, cur ^ 1);
      bn0 = *(const v8s*)(gB0 + (kc + 1) * 64);   // prefetch next B into VGPRs
      bn1 = *(const v8s*)(gB1 + (kc + 1) * 64);
    }
    v8s a[4];
#pragma unroll
    for (int f = 0; f < 4; f++) a[f] = *(const v8s*)&st[cur][wm * 4 + f][lane];
#pragma unroll
    for (int mf = 0; mf < 4; mf++) {
      acc[mf][0] = __builtin_amdgcn_mfma_f32_16x16x32_bf16(a[mf], bc0, acc[mf][0], 0, 0, 0);
      acc[mf][1] = __builtin_amdgcn_mfma_f32_16x16x32_bf16(a[mf], bc1, acc[mf][1], 0, 0, 0);
    }
    __syncthreads();  // next A buf staged; all waves done reading cur
    bc0 = bn0; bc1 = bn1;
  }
#undef STAGE_A

  // epilogue: C/D layout col = lane&15, row = quad*4 + reg; rn2 == 1.
  float scol[2] = {0.f, 0.f};
#pragma unroll
  for (int mf = 0; mf < 4; mf++) {
#pragma unroll
    for (int rr = 0; rr < 4; rr++) {
      int i = i0 + wm * 64 + mf * 16 + quad * 4 + rr;
      float srow = 0.f;
#pragma unroll
      for (int nf = 0; nf < 2; nf++) {
        int j = j0 + wn * 32 + nf * 16 + l15;
        float e = __expf((acc[mf][nf][rr] - 1.f) * INVT);
        bool ok = (j < NPIX) && (!diag || (i != j && i < NPIX));
        e = ok ? e : 0.f;
        srow += e;
        scol[nf] += e;
      }
      srow += __shfl_xor(srow, 1); srow += __shfl_xor(srow, 2);
      srow += __shfl_xor(srow, 4); srow += __shfl_xor(srow, 8);
      if (l15 == 0) Ered[wn][wm * 64 + mf * 16 + quad * 4 + rr] = srow;
    }
  }
  if (!diag) {
#pragma unroll
    for (int nf = 0; nf < 2; nf++) {
      float s = scol[nf];
      s += __shfl_xor(s, 16); s += __shfl_xor(s, 32);
      if (quad == 0) Ecol[wm][wn * 32 + nf * 16 + l15] = s;
    }
  }
  __syncthreads();
  if (tid < 128) {
    E9[((size_t)img * NT9 + jt) * NROWPAD + i0 + tid] =
        Ered[0][tid] + Ered[1][tid] + Ered[2][tid] + Ered[3][tid];
    if (!diag)
      E9[((size_t)img * NT9 + it) * NROWPAD + j0 + tid] = Ecol[0][tid] + Ecol[1][tid];
  }
}

// ---- K3: per-image losses + ticket-fused cross-image aggregation ----
// 1024 threads: 16-block latency-bound kernel, max TLP on the dependent-load
// chains (E9 9-slot sums, sums9 9-tile reduce, pair dots).
__global__ __launch_bounds__(1024) void k_imgfinal(const float* __restrict__ sums9,
                                                   const int* __restrict__ labels,
                                                   const float* __restrict__ cnt9,
                                                   const float* __restrict__ E9,
                                                   const float* __restrict__ is_forged,
                                                   unsigned* __restrict__ counter,
                                                   float* __restrict__ per_img,
                                                   float* __restrict__ out) {
  int b = blockIdx.x, tid = threadIdx.x;
  int wave = tid >> 6, lane = tid & 63;
  __shared__ float ssum[NLBL * DIM];  // 16 KB reduced per-label sums
  __shared__ float sCnt[NLBL], sR[NLBL][NLBL];
  __shared__ float sLog, sNA;
  if (tid < NLBL) {
    float s = 0.f;
#pragma unroll
    for (int g = 0; g < NT9; g++) s += cnt9[((size_t)b * NT9 + g) * NLBL + tid];
    sCnt[tid] = s;
  }
  if (tid == 0) { sLog = 0.f; sNA = 0.f; }
  for (int o = tid; o < NLBL * DIM; o += 1024) {
    float s = 0.f;
#pragma unroll
    for (int g = 0; g < NT9; g++) s += sums9[((size_t)(b * NT9 + g) * NLBL * DIM) + o];
    ssum[o] = s;
  }
  __syncthreads();
  float ll = 0.f, na = 0.f;
  for (int p = tid; p < NPIX; p += 1024) {
    int lab = labels[b * NROWPAD + p];
    if (sCnt[lab] >= 1.5f) {
      float e = 0.f;
#pragma unroll
      for (int s = 0; s < NT9; s++) e += E9[((size_t)b * NT9 + s) * NROWPAD + p];
      ll += __logf(e + 1e-6f);
      na += 1.f;
    }
  }
  ll = wave_reduce(ll); na = wave_reduce(na);
  if (lane == 0) { atomicAdd(&sLog, ll); atomicAdd(&sNA, na); }
  for (int t = wave; t < 36; t += 16) {
    int a = 0, tt = t;
    while (tt >= NLBL - a) { tt -= NLBL - a; a++; }
    int bb = a + tt;
    float d0 = 0.f;
    for (int k = lane; k < DIM; k += 64) d0 += ssum[a * DIM + k] * ssum[bb * DIM + k];
    d0 = wave_reduce(d0);
    if (lane == 0) sR[a][bb] = d0;
  }
  __syncthreads();
  if (tid == 0) {
    float spos = 0.f;
    for (int l = 0; l < NLBL; l++) {
      float c = sCnt[l];
      if (c >= 1.5f) spos += (sR[l][l] - c) * INVT / (c - 1.f) - c * INVT;
    }
    float nA = sNA;
    float sc = nA > 0.f ? (sLog - spos) / nA : 0.f;
    float scv = nA > 0.f ? 1.f : 0.f;
    float inv[NLBL]; int present[NLBL]; int nPres = 0;
    for (int l = 0; l < NLBL; l++) {
      present[l] = sCnt[l] > 0.f;
      nPres += present[l];
      inv[l] = 1.f / fmaxf(sCnt[l], 1.f);
    }
    float sepsum = 0.f; int npairs = 0;
    for (int a = 0; a < NLBL; a++)
      for (int c = a + 1; c < NLBL; c++)
        if (present[a] && present[c]) {
          float sq_ = sR[a][a] * inv[a] * inv[a] + sR[c][c] * inv[c] * inv[c]
                    - 2.f * sR[a][c] * inv[a] * inv[c];
          float dd = sqrtf(fmaxf(sq_, 0.f));
          sepsum += fmaxf(2.f - dd, 0.f);
          npairs++;
        }
    float sep = npairs > 0 ? sepsum / (float)npairs : 0.f;
    float sepv = nPres >= 2 ? 1.f : 0.f;
    float inst = 0.f; int nlbl = 0;
    for (int l = 0; l < NLBL; l++) {
      float var = 1.f - sR[l][l] * inv[l] * inv[l];  // q_l/c = 1
      if (sCnt[l] >= 2.f && var > 0.1f) { inst += var - 0.1f; nlbl++; }
    }
    float unif = nlbl > 0 ? inst / (float)nlbl : 0.f;
    float unifv = nlbl > 0 ? 1.f : 0.f;
    float tot2 = 0.f;
    for (int a = 0; a < NLBL; a++) {
      tot2 += sR[a][a];
      for (int c = a + 1; c < NLBL; c++) tot2 += 2.f * sR[a][c];
    }
    float Nf = (float)NPIX;
    float var_all = 1.f - tot2 / (Nf * Nf);  // totq/N = 1
    float uniu = var_all > 0.1f ? var_all - 0.1f : 0.f;
    float uniuv = var_all > 0.1f ? 1.f : 0.f;
    bool isf = is_forged[b] >= 0.5f;
    per_img[b * 6 + 0] = sc;
    per_img[b * 6 + 1] = scv;
    per_img[b * 6 + 2] = sep;
    per_img[b * 6 + 3] = sepv;
    per_img[b * 6 + 4] = isf ? unif : uniu;
    per_img[b * 6 + 5] = isf ? unifv : uniuv;
    __threadfence();  // release per_img before the ticket
    unsigned tk = atomicAdd(counter, 1u);
    if (tk == NIMG - 1) {  // last block aggregates
      __threadfence();
      float accv[3] = {0.f, 0.f, 0.f}, accn[3] = {0.f, 0.f, 0.f};
      for (int bb = 0; bb < NIMG; bb++)
        for (int m = 0; m < 3; m++) {
          float v = per_img[bb * 6 + m * 2], val = per_img[bb * 6 + m * 2 + 1];
          accv[m] += v * val; accn[m] += val;
        }
      float scA = accn[0] > 0.f ? accv[0] / accn[0] : 0.f;
      float sepA = accn[1] > 0.f ? accv[1] / accn[1] : 0.f;
      float uniA = accn[2] > 0.f ? accv[2] / accn[2] : 0.f;
      out[0] = 1.0f * scA + 0.5f * sepA + 0.5f * uniA;
    }
  }
}

extern "C" void kernel_launch(void* const* d_in, const int* in_sizes, int n_in,
                              void* d_out, int out_size, void* d_ws, size_t ws_size,
                              hipStream_t stream) {
  const float* emb = (const float*)d_in[0];
  const float* masks = (const float*)d_in[1];
  const float* isf = (const float*)d_in[2];
  float* out = (float*)d_out;
  char* ws = (char*)d_ws;
  size_t off = 0;
  uint4* bfemb4 = (uint4*)(ws + off);
  off += (size_t)NIMG * NGRP * 16 * 64 * 16;                      // 18.9 MB fragment-ordered bf16
  float* E9 = (float*)(ws + off);     off += sizeof(float) * NIMG * NT9 * NROWPAD;    // 663 KB
  float* sums9 = (float*)(ws + off);  off += sizeof(float) * NIMG * NT9 * NLBL * DIM; // 2.36 MB
  int* labels = (int*)(ws + off);     off += sizeof(int) * NIMG * NROWPAD;
  float* cnt9 = (float*)(ws + off);   off += sizeof(float) * NIMG * NT9 * NLBL;
  float* per_img = (float*)(ws + off); off += sizeof(float) * NIMG * 6;
  off = (off + 127) & ~(size_t)127;
  unsigned* counter = (unsigned*)(ws + off); off += 128;

  // 3 launches; no memset (owner-writes only; ticket zeroed by k_packsum)
  k_packsum<<<dim3(18, NIMG), 512, 0, stream>>>(emb, masks, (uint2*)bfemb4, sums9,
                                                labels, cnt9, counter);
  k_epass9<<<45 * NIMG, 512, 0, stream>>>(bfemb4, E9);
  k_imgfinal<<<NIMG, 1024, 0, stream>>>(sums9, labels, cnt9, E9, isf, counter, per_img, out);
}

// Round 8
// 121.388 us; speedup vs baseline: 1.0429x; 1.0429x over previous
//
#include <hip/hip_runtime.h>
#include <math.h>

#define NPIX 1089
#define DIM 512
#define NIMG 16
#define NLBL 8      // labels 0..6 used, 7 = padding bucket
#define NMASK 6
#define INVT 14.2857142857142857f  // 1/0.07

#define NGRP 72     // 16-row groups per image (72*16 = 1152 padded rows)
#define NROWPAD 1152
#define NT9 9       // 128-row tiles per dim

// Embeddings are unit-normalized by the module, so rn2 == 1 (+-2e-7):
// max-subtract constant, q_l (= cnt_l), totq (= NPIX) collapse.
//
// bfemb fragment-ordered layout (uint4 units):
//   index = ((img*NGRP + g)*16 + kc)*64 + (q*16 + m),  row = g*16+m, hw = kc*32 + q*8
// => any MFMA A/B fragment load is ONE contiguous 1KB wave load, and the
//    same chunk is ONE global_load_lds_dwordx4 wave load into linear LDS.
//
// E9[img][s][1152]: 9 owner-slots per image; each (rowgroup,slot) written by
// exactly ONE epass block (plain stores, no memset, no atomics).
//
// Lessons: R9 -- don't fuse cold tails into hot kernels (LDS/VGPR tax).
// R10/R11 -- standalone trivial kernels cost ~8us+gap; duplicate their work.
// R12 -- epass was L2-latency-bound at 11 waves/CU; widened to 8 waves/block.
// R13 -- LDS-stage per-kc chunks once (global_load_lds w=16, linear) -> -10.7us.
// R16 -- fused ticket tail REGRESSED +17us: device-scope __threadfence per
// block = buffer_wbl2/inv x720 (XCD L2s non-coherent). Keep 3 kernels.
// R17/R18 -- counted-vmcnt pipeline NEUTRAL vs plain syncthreads dbuf
// (reproduces m131-m140); the binding pipe isn't load latency.
// R19/R20 -- hybrid B-direct (A staged, B global->VGPR) REGRESSED +4us:
// doubled B L2 reads + per-kc vmcnt dep before MFMA outweigh the LDS-BW
// saving. epass6's 2-buffer loop is a multi-constraint local optimum
// (LDS ~ MFMA ~ L2 ~ barrier, none dominant); stop restructuring it.
// R21 -- R7 bench died at container level (byte-identical source passed in
// R5 at 122.6us; farm was degraded: acquire 121s). Resubmit unchanged.
// Budget model: totals == ~88us harness fill poison + ours (~35us):
// packsum ~11 (HBM-floor ~9.4), epass ~9 (floor ~6), imgfinal ~4, gaps ~3.

typedef short v8s __attribute__((ext_vector_type(8)));
typedef float v4f __attribute__((ext_vector_type(4)));

__device__ __forceinline__ float wave_reduce(float x) {
#pragma unroll
  for (int o = 32; o > 0; o >>= 1) x += __shfl_xor(x, o, 64);
  return x;
}
__device__ __forceinline__ unsigned bfbits(float x) {  // fp32 -> bf16 bits, RNE
  unsigned u = __float_as_uint(x);
  return (u + 0x7FFFu + ((u >> 16) & 1u)) >> 16;
}
__device__ __forceinline__ unsigned pk(float lo, float hi) {
  return bfbits(lo) | (bfbits(hi) << 16);
}

// -------- K1: fused labels + pack (fp32 -> fragment-ordered bf16) + partial sums ----
__global__ __launch_bounds__(512) void k_packsum(const float* __restrict__ emb,
                                                 const float* __restrict__ masks,
                                                 uint2* __restrict__ bfemb2,
                                                 float* __restrict__ sums9,
                                                 int* __restrict__ labels,
                                                 float* __restrict__ cnt9,
                                                 unsigned* __restrict__ counter) {
  int b = blockIdx.y;
  int g9 = blockIdx.x >> 1, dh = blockIdx.x & 1;  // 128-row group, 256-dim half
  int tid = threadIdx.x, dd = tid & 63, w4 = tid >> 6, lane = tid & 63;
  __shared__ float msum[NMASK];
  __shared__ int slab[128];
  __shared__ int scnt[NLBL];
  __shared__ float4 red[8 * 8 * 64];  // [l][w4][dd], 64 KB
  if (tid < NMASK) msum[tid] = 0.f;
  if (tid < NLBL) scnt[tid] = 0;
  if (b == 0 && blockIdx.x == 0 && tid == 0) *counter = 0u;
  __syncthreads();
  // per-channel mask sums (active test) -- L2-hot
  {
    float am[NMASK] = {0.f, 0.f, 0.f, 0.f, 0.f, 0.f};
    for (int p = tid; p < NPIX; p += 512) {
#pragma unroll
      for (int c = 0; c < NMASK; c++) am[c] += masks[((size_t)b * NMASK + c) * NPIX + p];
    }
#pragma unroll
    for (int c = 0; c < NMASK; c++) {
      float v = wave_reduce(am[c]);
      if (lane == 0) atomicAdd(&msum[c], v);
    }
  }
  __syncthreads();
  if (tid < 128) {
    int r = g9 * 128 + tid;
    int lab = 7;
    if (r < NPIX) {
      lab = 0;
#pragma unroll
      for (int c = 0; c < NMASK; c++) {
        float mv = masks[((size_t)b * NMASK + c) * NPIX + r];
        if (mv > 0.5f && msum[c] > 0.f) lab = c + 1;  // ascending overwrite == max over hits
      }
    }
    slab[tid] = lab;
    if (dh == 0) {
      labels[b * NROWPAD + r] = lab;
      if (r < NPIX) atomicAdd(&scnt[lab], 1);   // exclude pad rows
    }
  }
  __syncthreads();
  if (dh == 0 && tid < NLBL) cnt9[((size_t)b * NT9 + g9) * NLBL + tid] = (float)scnt[tid];
  float4 fa0 = {0,0,0,0}, fa1 = {0,0,0,0}, fa2 = {0,0,0,0}, fa3 = {0,0,0,0};
  float4 fa4 = {0,0,0,0}, fa5 = {0,0,0,0}, fa6 = {0,0,0,0}, fa7 = {0,0,0,0};
  int kc = dh * 8 + (dd >> 3), q = (dd >> 1) & 3, half = dd & 1;
#pragma unroll
  for (int k = 0; k < 16; k++) {
    int r = g9 * 128 + w4 + k * 8;           // wave-uniform row
    bool v = r < NPIX;
    int rc = v ? r : (NPIX - 1);
    float4 x = ((const float4*)(emb + (size_t)(b * NPIX + rc) * DIM))[dh * 64 + dd];
    if (!v) x = make_float4(0.f, 0.f, 0.f, 0.f);
    uint2 o = make_uint2(pk(x.x, x.y), pk(x.z, x.w));
    bfemb2[((((size_t)(b * NGRP + (r >> 4)) * 16 + kc) * 64) + q * 16 + (r & 15)) * 2 + half] = o;
    int lab = __builtin_amdgcn_readfirstlane(slab[r - g9 * 128]);
    switch (lab) {
      case 0: fa0.x += x.x; fa0.y += x.y; fa0.z += x.z; fa0.w += x.w; break;
      case 1: fa1.x += x.x; fa1.y += x.y; fa1.z += x.z; fa1.w += x.w; break;
      case 2: fa2.x += x.x; fa2.y += x.y; fa2.z += x.z; fa2.w += x.w; break;
      case 3: fa3.x += x.x; fa3.y += x.y; fa3.z += x.z; fa3.w += x.w; break;
      case 4: fa4.x += x.x; fa4.y += x.y; fa4.z += x.z; fa4.w += x.w; break;
      case 5: fa5.x += x.x; fa5.y += x.y; fa5.z += x.z; fa5.w += x.w; break;
      case 6: fa6.x += x.x; fa6.y += x.y; fa6.z += x.z; fa6.w += x.w; break;
      default: fa7.x += x.x; fa7.y += x.y; fa7.z += x.z; fa7.w += x.w; break;
    }
  }
  red[(0 * 8 + w4) * 64 + dd] = fa0; red[(1 * 8 + w4) * 64 + dd] = fa1;
  red[(2 * 8 + w4) * 64 + dd] = fa2; red[(3 * 8 + w4) * 64 + dd] = fa3;
  red[(4 * 8 + w4) * 64 + dd] = fa4; red[(5 * 8 + w4) * 64 + dd] = fa5;
  red[(6 * 8 + w4) * 64 + dd] = fa6; red[(7 * 8 + w4) * 64 + dd] = fa7;
  __syncthreads();
  int l = tid >> 6, d2 = tid & 63;
  float4 s = {0,0,0,0};
#pragma unroll
  for (int ww = 0; ww < 8; ww++) {
    float4 t = red[(l * 8 + ww) * 64 + d2];
    s.x += t.x; s.y += t.y; s.z += t.z; s.w += t.w;
  }
  *(float4*)&sums9[(((size_t)(b * NT9 + g9) * NLBL + l) * DIM) + dh * 256 + d2 * 4] = s;
}

// -------- K2: E-pass, symmetric tiles (it<=jt), 8 waves/block (64x32 per wave),
//              LDS-staged double-buffered K-loop (global_load_lds w=16),
//              ds_read_b128 fragment reads, LDS-merged owner-slot epilogue ----
__global__ __launch_bounds__(512) void k_epass6(const uint4* __restrict__ bfemb4,
                                                float* __restrict__ E9) {
  int n = blockIdx.x;                          // 45*16 = 720
  int img = ((n & 7) << 1) | ((n >> 3) & 1);   // 2 images per XCD
  int t = n >> 4;                              // 0..44 upper-tri tile
  int it = 0, rem = t;
  while (rem >= NT9 - it) { rem -= NT9 - it; it++; }
  int jt = it + rem;
  int i0 = it * 128, j0 = jt * 128;
  bool diag = (it == jt);
  int tid = threadIdx.x, lane = tid & 63, w = tid >> 6;
  int wm = w >> 2, wn = w & 3;                 // 2 row-waves x 4 col-waves
  int quad = lane >> 4, l15 = lane & 15;
  // st[buf][ab][chunk][lane16B]: linear == global fragment order (no swizzle
  // needed; ds_read_b128 of a 1KB chunk is the conflict-free m97 pattern)
  __shared__ uint4 st[2][2][8][64];            // 32 KB staging
  __shared__ float Ered[4][128];               // 4 col-wave partials per row
  __shared__ float Ecol[2][128];               // 2 row-wave partials per col

  // per-wave global source: wave w stages A-group it*8+w, B-group jt*8+w
  size_t gA = ((size_t)(img * NGRP + it * 8 + w) * 16) * 64 + lane;
  size_t gB = ((size_t)(img * NGRP + jt * 8 + w) * 16) * 64 + lane;
  int bsel = diag ? 0 : 1;                     // diag: B frags read from A region

#define STAGE(kc, buf)                                                          \
  {                                                                             \
    __builtin_amdgcn_global_load_lds(                                           \
        (const __attribute__((address_space(1))) void*)(bfemb4 + gA + (kc) * 64), \
        (__attribute__((address_space(3))) void*)&st[buf][0][w][0], 16, 0, 0);  \
    if (!diag)                                                                  \
      __builtin_amdgcn_global_load_lds(                                         \
          (const __attribute__((address_space(1))) void*)(bfemb4 + gB + (kc) * 64), \
          (__attribute__((address_space(3))) void*)&st[buf][1][w][0], 16, 0, 0); \
  }

  v4f acc[4][2];
#pragma unroll
  for (int mf = 0; mf < 4; mf++)
#pragma unroll
    for (int nf = 0; nf < 2; nf++) acc[mf][nf] = (v4f){0.f, 0.f, 0.f, 0.f};

  STAGE(0, 0);
  __syncthreads();  // vmcnt(0) drain: buf0 ready
#pragma unroll
  for (int kc = 0; kc < 16; kc++) {
    int cur = kc & 1;
    if (kc < 15) STAGE(kc + 1, cur ^ 1);
    v8s a[4], b[2];
#pragma unroll
    for (int f = 0; f < 4; f++) a[f] = *(const v8s*)&st[cur][0][wm * 4 + f][lane];
#pragma unroll
    for (int f = 0; f < 2; f++) b[f] = *(const v8s*)&st[cur][bsel][wn * 2 + f][lane];
#pragma unroll
    for (int mf = 0; mf < 4; mf++)
#pragma unroll
      for (int nf = 0; nf < 2; nf++)
        acc[mf][nf] = __builtin_amdgcn_mfma_f32_16x16x32_bf16(a[mf], b[nf],
                                                              acc[mf][nf], 0, 0, 0);
    __syncthreads();  // next buf staged; all waves done reading cur
  }
#undef STAGE

  // epilogue: C/D layout col = lane&15, row = quad*4 + reg; rn2 == 1.
  float scol[2] = {0.f, 0.f};
#pragma unroll
  for (int mf = 0; mf < 4; mf++) {
#pragma unroll
    for (int rr = 0; rr < 4; rr++) {
      int i = i0 + wm * 64 + mf * 16 + quad * 4 + rr;
      float srow = 0.f;
#pragma unroll
      for (int nf = 0; nf < 2; nf++) {
        int j = j0 + wn * 32 + nf * 16 + l15;
        float e = __expf((acc[mf][nf][rr] - 1.f) * INVT);
        bool ok = (j < NPIX) && (!diag || (i != j && i < NPIX));
        e = ok ? e : 0.f;
        srow += e;
        scol[nf] += e;
      }
      srow += __shfl_xor(srow, 1); srow += __shfl_xor(srow, 2);
      srow += __shfl_xor(srow, 4); srow += __shfl_xor(srow, 8);
      if (l15 == 0) Ered[wn][wm * 64 + mf * 16 + quad * 4 + rr] = srow;
    }
  }
  if (!diag) {
#pragma unroll
    for (int nf = 0; nf < 2; nf++) {
      float s = scol[nf];
      s += __shfl_xor(s, 16); s += __shfl_xor(s, 32);
      if (quad == 0) Ecol[wm][wn * 32 + nf * 16 + l15] = s;
    }
  }
  __syncthreads();
  if (tid < 128) {
    E9[((size_t)img * NT9 + jt) * NROWPAD + i0 + tid] =
        Ered[0][tid] + Ered[1][tid] + Ered[2][tid] + Ered[3][tid];
    if (!diag)
      E9[((size_t)img * NT9 + it) * NROWPAD + j0 + tid] = Ecol[0][tid] + Ecol[1][tid];
  }
}

// ---- K3: per-image losses + ticket-fused cross-image aggregation ----
// 1024 threads: 16-block latency-bound kernel, max TLP on the dependent-load
// chains (E9 9-slot sums, sums9 9-tile reduce, pair dots).
__global__ __launch_bounds__(1024) void k_imgfinal(const float* __restrict__ sums9,
                                                   const int* __restrict__ labels,
                                                   const float* __restrict__ cnt9,
                                                   const float* __restrict__ E9,
                                                   const float* __restrict__ is_forged,
                                                   unsigned* __restrict__ counter,
                                                   float* __restrict__ per_img,
                                                   float* __restrict__ out) {
  int b = blockIdx.x, tid = threadIdx.x;
  int wave = tid >> 6, lane = tid & 63;
  __shared__ float ssum[NLBL * DIM];  // 16 KB reduced per-label sums
  __shared__ float sCnt[NLBL], sR[NLBL][NLBL];
  __shared__ float sLog, sNA;
  if (tid < NLBL) {
    float s = 0.f;
#pragma unroll
    for (int g = 0; g < NT9; g++) s += cnt9[((size_t)b * NT9 + g) * NLBL + tid];
    sCnt[tid] = s;
  }
  if (tid == 0) { sLog = 0.f; sNA = 0.f; }
  for (int o = tid; o < NLBL * DIM; o += 1024) {
    float s = 0.f;
#pragma unroll
    for (int g = 0; g < NT9; g++) s += sums9[((size_t)(b * NT9 + g) * NLBL * DIM) + o];
    ssum[o] = s;
  }
  __syncthreads();
  float ll = 0.f, na = 0.f;
  for (int p = tid; p < NPIX; p += 1024) {
    int lab = labels[b * NROWPAD + p];
    if (sCnt[lab] >= 1.5f) {
      float e = 0.f;
#pragma unroll
      for (int s = 0; s < NT9; s++) e += E9[((size_t)b * NT9 + s) * NROWPAD + p];
      ll += __logf(e + 1e-6f);
      na += 1.f;
    }
  }
  ll = wave_reduce(ll); na = wave_reduce(na);
  if (lane == 0) { atomicAdd(&sLog, ll); atomicAdd(&sNA, na); }
  for (int t = wave; t < 36; t += 16) {
    int a = 0, tt = t;
    while (tt >= NLBL - a) { tt -= NLBL - a; a++; }
    int bb = a + tt;
    float d0 = 0.f;
    for (int k = lane; k < DIM; k += 64) d0 += ssum[a * DIM + k] * ssum[bb * DIM + k];
    d0 = wave_reduce(d0);
    if (lane == 0) sR[a][bb] = d0;
  }
  __syncthreads();
  if (tid == 0) {
    float spos = 0.f;
    for (int l = 0; l < NLBL; l++) {
      float c = sCnt[l];
      if (c >= 1.5f) spos += (sR[l][l] - c) * INVT / (c - 1.f) - c * INVT;
    }
    float nA = sNA;
    float sc = nA > 0.f ? (sLog - spos) / nA : 0.f;
    float scv = nA > 0.f ? 1.f : 0.f;
    float inv[NLBL]; int present[NLBL]; int nPres = 0;
    for (int l = 0; l < NLBL; l++) {
      present[l] = sCnt[l] > 0.f;
      nPres += present[l];
      inv[l] = 1.f / fmaxf(sCnt[l], 1.f);
    }
    float sepsum = 0.f; int npairs = 0;
    for (int a = 0; a < NLBL; a++)
      for (int c = a + 1; c < NLBL; c++)
        if (present[a] && present[c]) {
          float sq_ = sR[a][a] * inv[a] * inv[a] + sR[c][c] * inv[c] * inv[c]
                    - 2.f * sR[a][c] * inv[a] * inv[c];
          float dd = sqrtf(fmaxf(sq_, 0.f));
          sepsum += fmaxf(2.f - dd, 0.f);
          npairs++;
        }
    float sep = npairs > 0 ? sepsum / (float)npairs : 0.f;
    float sepv = nPres >= 2 ? 1.f : 0.f;
    float inst = 0.f; int nlbl = 0;
    for (int l = 0; l < NLBL; l++) {
      float var = 1.f - sR[l][l] * inv[l] * inv[l];  // q_l/c = 1
      if (sCnt[l] >= 2.f && var > 0.1f) { inst += var - 0.1f; nlbl++; }
    }
    float unif = nlbl > 0 ? inst / (float)nlbl : 0.f;
    float unifv = nlbl > 0 ? 1.f : 0.f;
    float tot2 = 0.f;
    for (int a = 0; a < NLBL; a++) {
      tot2 += sR[a][a];
      for (int c = a + 1; c < NLBL; c++) tot2 += 2.f * sR[a][c];
    }
    float Nf = (float)NPIX;
    float var_all = 1.f - tot2 / (Nf * Nf);  // totq/N = 1
    float uniu = var_all > 0.1f ? var_all - 0.1f : 0.f;
    float uniuv = var_all > 0.1f ? 1.f : 0.f;
    bool isf = is_forged[b] >= 0.5f;
    per_img[b * 6 + 0] = sc;
    per_img[b * 6 + 1] = scv;
    per_img[b * 6 + 2] = sep;
    per_img[b * 6 + 3] = sepv;
    per_img[b * 6 + 4] = isf ? unif : uniu;
    per_img[b * 6 + 5] = isf ? unifv : uniuv;
    __threadfence();  // release per_img before the ticket
    unsigned tk = atomicAdd(counter, 1u);
    if (tk == NIMG - 1) {  // last block aggregates
      __threadfence();
      float accv[3] = {0.f, 0.f, 0.f}, accn[3] = {0.f, 0.f, 0.f};
      for (int bb = 0; bb < NIMG; bb++)
        for (int m = 0; m < 3; m++) {
          float v = per_img[bb * 6 + m * 2], val = per_img[bb * 6 + m * 2 + 1];
          accv[m] += v * val; accn[m] += val;
        }
      float scA = accn[0] > 0.f ? accv[0] / accn[0] : 0.f;
      float sepA = accn[1] > 0.f ? accv[1] / accn[1] : 0.f;
      float uniA = accn[2] > 0.f ? accv[2] / accn[2] : 0.f;
      out[0] = 1.0f * scA + 0.5f * sepA + 0.5f * uniA;
    }
  }
}

extern "C" void kernel_launch(void* const* d_in, const int* in_sizes, int n_in,
                              void* d_out, int out_size, void* d_ws, size_t ws_size,
                              hipStream_t stream) {
  const float* emb = (const float*)d_in[0];
  const float* masks = (const float*)d_in[1];
  const float* isf = (const float*)d_in[2];
  float* out = (float*)d_out;
  char* ws = (char*)d_ws;
  size_t off = 0;
  uint4* bfemb4 = (uint4*)(ws + off);
  off += (size_t)NIMG * NGRP * 16 * 64 * 16;                      // 18.9 MB fragment-ordered bf16
  float* E9 = (float*)(ws + off);     off += sizeof(float) * NIMG * NT9 * NROWPAD;    // 663 KB
  float* sums9 = (float*)(ws + off);  off += sizeof(float) * NIMG * NT9 * NLBL * DIM; // 2.36 MB
  int* labels = (int*)(ws + off);     off += sizeof(int) * NIMG * NROWPAD;
  float* cnt9 = (float*)(ws + off);   off += sizeof(float) * NIMG * NT9 * NLBL;
  float* per_img = (float*)(ws + off); off += sizeof(float) * NIMG * 6;
  off = (off + 127) & ~(size_t)127;
  unsigned* counter = (unsigned*)(ws + off); off += 128;

  // 3 launches; no memset (owner-writes only; ticket zeroed by k_packsum)
  k_packsum<<<dim3(18, NIMG), 512, 0, stream>>>(emb, masks, (uint2*)bfemb4, sums9,
                                                labels, cnt9, counter);
  k_epass6<<<45 * NIMG, 512, 0, stream>>>(bfemb4, E9);
  k_imgfinal<<<NIMG, 1024, 0, stream>>>(sums9, labels, cnt9, E9, isf, counter, per_img, out);
}